// Round 16
// baseline (61.104 us; speedup 1.0000x reference)
//
#include <hip/hip_runtime.h>
#include <hip/hip_bf16.h>
#include <cstdint>
#include <cstddef>

#define B_ 8
#define C_ 64
#define CI 32
#define N_ 4096
#define LOG2E 1.44269504088896340736f

typedef __attribute__((ext_vector_type(8))) short bf16x8;
typedef __attribute__((ext_vector_type(4))) float f32x4;

static __device__ __forceinline__ ushort f2bf(float x) {
  union { float f; uint32_t u; } v; v.f = x;
  uint32_t r = v.u + 0x7FFFu + ((v.u >> 16) & 1u);
  return (ushort)(r >> 16);
}

static __device__ __forceinline__ uint32_t cvt_pk_bf16(float lo, float hi) {
  uint32_t r;
  asm("v_cvt_pk_bf16_f32 %0, %1, %2" : "=v"(r) : "v"(lo), "v"(hi));
  return r;
}

// -------- Kernel 1: fused 1x1-conv projections, scalar W loads (r14) -------
__global__ __launch_bounds__(512) void proj_kernel(
    const float* __restrict__ x,
    const float* __restrict__ Wg, const float* __restrict__ bg,
    const float* __restrict__ Wt, const float* __restrict__ bt,
    const float* __restrict__ Wp, const float* __restrict__ bp,
    ushort* __restrict__ theta_t, ushort* __restrict__ phi_t,
    ushort* __restrict__ gmat)
{
  const int t = threadIdx.x;
  const int b = blockIdx.y;
  const int n = blockIdx.x * 64 + (t & 63);
  const int dg = __builtin_amdgcn_readfirstlane(t >> 6);  // uniform 0..7
  const float* xb = x + ((size_t)b * C_) * N_ + n;
  const float* WtR = Wt + dg * 4 * C_;
  const float* WpR = Wp + dg * 4 * C_;
  const float* WgR = Wg + dg * 4 * C_;

  float at[4], ap[4], ag[4];
  #pragma unroll
  for (int i = 0; i < 4; ++i) {
    at[i] = bt[dg * 4 + i]; ap[i] = bp[dg * 4 + i]; ag[i] = bg[dg * 4 + i];
  }

  #pragma unroll
  for (int c0 = 0; c0 < C_; c0 += 4) {
    float xv[4];
    #pragma unroll
    for (int j = 0; j < 4; ++j) xv[j] = xb[(size_t)(c0 + j) * N_];
    #pragma unroll
    for (int i = 0; i < 4; ++i) {
      const float4 wt4 = *(const float4*)&WtR[i * C_ + c0];
      const float4 wp4 = *(const float4*)&WpR[i * C_ + c0];
      const float4 wg4 = *(const float4*)&WgR[i * C_ + c0];
      at[i] = fmaf(wt4.x, xv[0], at[i]); at[i] = fmaf(wt4.y, xv[1], at[i]);
      at[i] = fmaf(wt4.z, xv[2], at[i]); at[i] = fmaf(wt4.w, xv[3], at[i]);
      ap[i] = fmaf(wp4.x, xv[0], ap[i]); ap[i] = fmaf(wp4.y, xv[1], ap[i]);
      ap[i] = fmaf(wp4.z, xv[2], ap[i]); ap[i] = fmaf(wp4.w, xv[3], ap[i]);
      ag[i] = fmaf(wg4.x, xv[0], ag[i]); ag[i] = fmaf(wg4.y, xv[1], ag[i]);
      ag[i] = fmaf(wg4.w * 0.f + wg4.z, xv[2], ag[i]); ag[i] = fmaf(wg4.w, xv[3], ag[i]);
    }
  }

  uint2 wt2, wp2;
  wt2.x = (uint32_t)f2bf(at[0] * LOG2E) | ((uint32_t)f2bf(at[1] * LOG2E) << 16);
  wt2.y = (uint32_t)f2bf(at[2] * LOG2E) | ((uint32_t)f2bf(at[3] * LOG2E) << 16);
  wp2.x = (uint32_t)f2bf(ap[0]) | ((uint32_t)f2bf(ap[1]) << 16);
  wp2.y = (uint32_t)f2bf(ap[2]) | ((uint32_t)f2bf(ap[3]) << 16);
  *(uint2*)(theta_t + ((size_t)(b * N_) + n) * CI + dg * 4) = wt2;
  *(uint2*)(phi_t   + ((size_t)(b * N_) + n) * CI + dg * 4) = wp2;
  #pragma unroll
  for (int i = 0; i < 4; ++i)
    gmat[((size_t)(b * CI) + dg * 4 + i) * N_ + n] = f2bf(ag[i]);
}

// -------- Kernel 2: flash attention, 1-deep manually pipelined PV ----------
// Per body: QK(S) | fence(prev writes ~free) | issue P(S-1) reads |
// softmax(S) hides read | fence(reads ~free) | PV(S-1)+rescale(S-1) |
// write P(S). Drains move off the critical path.
#define BODY(S, DO_PREV)                                                      \
  {                                                                           \
    constexpr int sP = ((S) + 3) & 3;                                         \
    f32x4 cop;                                                                \
    cop[0] = mneg[S]; cop[1] = mneg[S]; cop[2] = mneg[S]; cop[3] = mneg[S];   \
    f32x4 f[4];                                                               \
    _Pragma("unroll")                                                         \
    for (int mt = 0; mt < 4; ++mt)                                            \
      f[mt] = __builtin_amdgcn_mfma_f32_16x16x32_bf16(                        \
          kf[mt], qfrag[S], cop, 0, 0, 0);                                    \
    /* fence1: previous body's P-writes complete (issued a body ago) */       \
    asm volatile("s_waitcnt lgkmcnt(0)" ::: "memory");                        \
    const bf16x8 pfA = *(const bf16x8*)prd[sP & 1][0];                        \
    const bf16x8 pfB = *(const bf16x8*)prd[sP & 1][1];                        \
    uint2 wv[4];                                                              \
    float lsum = 0.f;                                                         \
    _Pragma("unroll")                                                         \
    for (int mt = 0; mt < 4; ++mt) {                                          \
      const float p0 = __builtin_amdgcn_exp2f(f[mt][0]);                      \
      const float p1 = __builtin_amdgcn_exp2f(f[mt][1]);                      \
      const float p2 = __builtin_amdgcn_exp2f(f[mt][2]);                      \
      const float p3 = __builtin_amdgcn_exp2f(f[mt][3]);                      \
      lsum += (p0 + p1) + (p2 + p3);                                          \
      wv[mt].x = cvt_pk_bf16(p0, p1);                                         \
      wv[mt].y = cvt_pk_bf16(p2, p3);                                         \
    }                                                                         \
    l_lane[S] += lsum;                                                        \
    /* fence2: our P(S-1) reads complete (hidden under softmax above) */      \
    asm volatile("s_waitcnt lgkmcnt(0)" ::: "memory");                        \
    if (DO_PREV) {                                                            \
      acc[sP][0] = __builtin_amdgcn_mfma_f32_16x16x32_bf16(                   \
          vf0[0], pfA, acc[sP][0], 0, 0, 0);                                  \
      acc[sP][1] = __builtin_amdgcn_mfma_f32_16x16x32_bf16(                   \
          vf1[0], pfA, acc[sP][1], 0, 0, 0);                                  \
      acc[sP][0] = __builtin_amdgcn_mfma_f32_16x16x32_bf16(                   \
          vf0[1], pfB, acc[sP][0], 0, 0, 0);                                  \
      acc[sP][1] = __builtin_amdgcn_mfma_f32_16x16x32_bf16(                   \
          vf1[1], pfB, acc[sP][1], 0, 0, 0);                                  \
      if (__any(l_lane[sP] > 0x1p40f)) {                                      \
        const float sc = 0x1p-64f;                                            \
        acc[sP][0] *= sc; acc[sP][1] *= sc; l_lane[sP] *= sc;                 \
        mneg[sP] -= 64.f;                                                     \
      }                                                                       \
    }                                                                         \
    _Pragma("unroll")                                                         \
    for (int mt = 0; mt < 4; ++mt)                                            \
      *(uint2*)pw[(S) & 1][mt] = wv[mt];                                      \
  }

__global__ __launch_bounds__(512) void attn_kernel(
    const ushort* __restrict__ theta_t,
    const ushort* __restrict__ phi_t,
    const ushort* __restrict__ gmat,
    const float* __restrict__ Ww, const float* __restrict__ bw,
    const float* __restrict__ x, float* __restrict__ out)
{
  __shared__ union {
    ushort pt[8][2][16 * 64];     // per-wave ping-pong P tiles (main loop)
    float  accS[4][32][64];       // merge acc slots (merge phase)
    float  yl[32 * 66];           // y tile (after final merge sync)
  } Sh;
  __shared__ float mlS[4][8][64]; // merge m/l slots
  __shared__ float WwL[C_ * CI];

  const int tid = threadIdx.x;
  const int lane = tid & 63;
  const int mh = tid >> 6;        // wave = m-eighth 0..7
  const int bid = blockIdx.x;
  const int b = bid & 7;          // batch -> XCD slot (K/V L2-resident)
  const int n0 = (bid >> 3) * 64;
  const int g4 = lane >> 4;
  const int c16 = lane & 15;
  const int sw = (c16 & 7) << 4;

  #pragma unroll
  for (int i = 0; i < 4; ++i) WwL[tid + i * 512] = Ww[tid + i * 512];

  bf16x8 qfrag[4];
  #pragma unroll
  for (int s = 0; s < 4; ++s)
    qfrag[s] = *(const bf16x8*)(theta_t +
        ((size_t)(b * N_ + n0 + s * 16 + c16)) * CI + g4 * 8);

  f32x4 acc[4][2];
  float mneg[4] = {0.f, 0.f, 0.f, 0.f};   // = -m_run[s]
  float l_lane[4] = {0.f, 0.f, 0.f, 0.f};
  #pragma unroll
  for (int s = 0; s < 4; ++s) {
    acc[s][0] = (f32x4){0.f, 0.f, 0.f, 0.f};
    acc[s][1] = (f32x4){0.f, 0.f, 0.f, 0.f};
  }

  const int mq0 = mh * 512;
  const ushort* kbase = phi_t + ((size_t)(b * N_ + mq0 + c16)) * CI + g4 * 8;
  const ushort* vb0 = gmat + ((size_t)(b * CI + c16)) * N_ + mq0 + g4 * 8;
  const ushort* vb1 = vb0 + (size_t)16 * N_;

  char* pw[2][4]; const char* prd[2][2];
  #pragma unroll
  for (int pb = 0; pb < 2; ++pb) {
    #pragma unroll
    for (int mt = 0; mt < 4; ++mt)
      pw[pb][mt] = (char*)Sh.pt[mh][pb] + ((c16 * 128 + mt * 32 + g4 * 8) ^ sw);
    #pragma unroll
    for (int ks = 0; ks < 2; ++ks)
      prd[pb][ks] = (const char*)Sh.pt[mh][pb] +
                    ((c16 * 128 + ks * 64 + g4 * 16) ^ sw);
  }

  bf16x8 kf[4], vf0[2], vf1[2];

  const int NT = 8;               // 512 rows / 64 per tile
  for (int t = 0; t < NT; ++t) {
    #pragma unroll
    for (int mt = 0; mt < 4; ++mt)
      kf[mt] = *(const bf16x8*)(kbase + (size_t)(t * 64 + mt * 16) * CI);

    BODY(0, (t > 0))              // PV(3 of t-1) uses vf from t-1 (still live)

    #pragma unroll
    for (int ks = 0; ks < 2; ++ks) {
      vf0[ks] = *(const bf16x8*)(vb0 + t * 64 + ks * 32);
      vf1[ks] = *(const bf16x8*)(vb1 + t * 64 + ks * 32);
    }

    BODY(1, true)
    BODY(2, true)
    BODY(3, true)
  }

  // epilogue: PV + rescale for (NT-1, 3); P(3) lives in buffer 1
  {
    asm volatile("s_waitcnt lgkmcnt(0)" ::: "memory");   // drain body-3 writes
    const bf16x8 pfA = *(const bf16x8*)prd[1][0];
    const bf16x8 pfB = *(const bf16x8*)prd[1][1];
    asm volatile("s_waitcnt lgkmcnt(0)" ::: "memory");   // drain reads
    acc[3][0] = __builtin_amdgcn_mfma_f32_16x16x32_bf16(vf0[0], pfA, acc[3][0], 0, 0, 0);
    acc[3][1] = __builtin_amdgcn_mfma_f32_16x16x32_bf16(vf1[0], pfA, acc[3][1], 0, 0, 0);
    acc[3][0] = __builtin_amdgcn_mfma_f32_16x16x32_bf16(vf0[1], pfB, acc[3][0], 0, 0, 0);
    acc[3][1] = __builtin_amdgcn_mfma_f32_16x16x32_bf16(vf1[1], pfB, acc[3][1], 0, 0, 0);
    if (__any(l_lane[3] > 0x1p40f)) {
      const float sc = 0x1p-64f;
      acc[3][0] *= sc; acc[3][1] *= sc; l_lane[3] *= sc;
      mneg[3] -= 64.f;
    }
  }

  // total l per q-column: sum the 4 g4 partials
  float m_run[4];
  #pragma unroll
  for (int s = 0; s < 4; ++s) {
    l_lane[s] += __shfl_xor(l_lane[s], 16);
    l_lane[s] += __shfl_xor(l_lane[s], 32);
    m_run[s] = -mneg[s];
  }

  // ---- split-m merge: max-aware flash combine, 3-round tree (r7-proven) ----
  #pragma unroll
  for (int r = 4; r >= 1; r >>= 1) {
    __syncthreads();
    if (mh >= r && mh < 2 * r) {
      float* ad = &Sh.accS[mh - r][0][0] + lane;
      float* md = &mlS[mh - r][0][0] + lane;
      #pragma unroll
      for (int s = 0; s < 4; ++s) {
        #pragma unroll
        for (int rr = 0; rr < 4; ++rr) {
          ad[(s * 8 + rr) * 64]     = acc[s][0][rr];
          ad[(s * 8 + 4 + rr) * 64] = acc[s][1][rr];
        }
        md[s * 64]       = m_run[s];
        md[(4 + s) * 64] = l_lane[s];
      }
    }
    __syncthreads();
    if (mh < r) {
      const float* as_ = &Sh.accS[mh][0][0] + lane;
      const float* ms_ = &mlS[mh][0][0] + lane;
      #pragma unroll
      for (int s = 0; s < 4; ++s) {
        const float mb = ms_[s * 64];
        const float lb = ms_[(4 + s) * 64];
        const float mM = fmaxf(m_run[s], mb);
        const float ea = __builtin_amdgcn_exp2f(m_run[s] - mM);
        const float eb = __builtin_amdgcn_exp2f(mb - mM);
        #pragma unroll
        for (int rr = 0; rr < 4; ++rr) {
          acc[s][0][rr] = acc[s][0][rr] * ea + as_[(s * 8 + rr) * 64] * eb;
          acc[s][1][rr] = acc[s][1][rr] * ea + as_[(s * 8 + 4 + rr) * 64] * eb;
        }
        l_lane[s] = l_lane[s] * ea + lb * eb;
        m_run[s] = mM;
      }
    }
  }
  __syncthreads();                // all merge reads done; Sh reusable as Yl

  float* const Yl = Sh.yl;        // aliases dead pt/accS (barrier-ordered)
  if (mh == 0) {
    #pragma unroll
    for (int s = 0; s < 4; ++s) {
      const float inv = 1.0f / l_lane[s];
      const int q = s * 16 + c16;
      #pragma unroll
      for (int rr = 0; rr < 4; ++rr) {
        Yl[(g4 * 4 + rr) * 66 + q]      = acc[s][0][rr] * inv;
        Yl[(16 + g4 * 4 + rr) * 66 + q] = acc[s][1][rr] * inv;
      }
    }
  }
  __syncthreads();

  // ---- fused out-projection + residual: out = Ww @ y + bw + x ----
  const int nl = tid & 63;
  const int cg = tid >> 6;
  float oacc[8];
  #pragma unroll
  for (int i = 0; i < 8; ++i) oacc[i] = bw[cg * 8 + i];
  #pragma unroll
  for (int d = 0; d < CI; ++d) {
    const float yv = Yl[d * 66 + nl];
    #pragma unroll
    for (int i = 0; i < 8; ++i)
      oacc[i] = fmaf(WwL[(cg * 8 + i) * CI + d], yv, oacc[i]);
  }
  #pragma unroll
  for (int i = 0; i < 8; ++i) {
    const size_t idx = ((size_t)(b * C_ + cg * 8 + i)) * N_ + n0 + nl;
    out[idx] = oacc[i] + x[idx];
  }
}

extern "C" void kernel_launch(void* const* d_in, const int* in_sizes, int n_in,
                              void* d_out, int out_size, void* d_ws, size_t ws_size,
                              hipStream_t stream) {
  const float* x  = (const float*)d_in[0];
  const float* Wg = (const float*)d_in[1];
  const float* bg = (const float*)d_in[2];
  const float* Wt = (const float*)d_in[3];
  const float* bt = (const float*)d_in[4];
  const float* Wp = (const float*)d_in[5];
  const float* bp = (const float*)d_in[6];
  const float* Ww = (const float*)d_in[7];
  const float* bw = (const float*)d_in[8];
  float* out = (float*)d_out;

  char* ws = (char*)d_ws;
  ushort* theta_t = (ushort*)(ws);
  ushort* phi_t   = (ushort*)(ws + (size_t)2 * 1024 * 1024);
  ushort* gmat    = (ushort*)(ws + (size_t)4 * 1024 * 1024);

  proj_kernel<<<dim3(N_ / 64, B_), 512, 0, stream>>>(
      x, Wg, bg, Wt, bt, Wp, bp, theta_t, phi_t, gmat);
  attn_kernel<<<dim3((N_ / 64) * B_), 512, 0, stream>>>(
      theta_t, phi_t, gmat, Ww, bw, x, out);
}

// Round 20
// 59.924 us; speedup vs baseline: 1.0197x; 1.0197x over previous
//
#include <hip/hip_runtime.h>
#include <hip/hip_bf16.h>
#include <cstdint>
#include <cstddef>

#define B_ 8
#define C_ 64
#define CI 32
#define N_ 4096
#define LOG2E 1.44269504088896340736f

typedef __attribute__((ext_vector_type(8))) short bf16x8;
typedef __attribute__((ext_vector_type(4))) float f32x4;

static __device__ __forceinline__ ushort f2bf(float x) {
  union { float f; uint32_t u; } v; v.f = x;
  uint32_t r = v.u + 0x7FFFu + ((v.u >> 16) & 1u);
  return (ushort)(r >> 16);
}

static __device__ __forceinline__ uint32_t cvt_pk_bf16(float lo, float hi) {
  uint32_t r;
  asm("v_cvt_pk_bf16_f32 %0, %1, %2" : "=v"(r) : "v"(lo), "v"(hi));
  return r;
}

// -------- Kernel 1: fused 1x1-conv projections, scalar W loads (r14) -------
__global__ __launch_bounds__(512) void proj_kernel(
    const float* __restrict__ x,
    const float* __restrict__ Wg, const float* __restrict__ bg,
    const float* __restrict__ Wt, const float* __restrict__ bt,
    const float* __restrict__ Wp, const float* __restrict__ bp,
    ushort* __restrict__ theta_t, ushort* __restrict__ phi_t,
    ushort* __restrict__ gmat)
{
  const int t = threadIdx.x;
  const int b = blockIdx.y;
  const int n = blockIdx.x * 64 + (t & 63);
  const int dg = __builtin_amdgcn_readfirstlane(t >> 6);  // uniform 0..7
  const float* xb = x + ((size_t)b * C_) * N_ + n;
  const float* WtR = Wt + dg * 4 * C_;
  const float* WpR = Wp + dg * 4 * C_;
  const float* WgR = Wg + dg * 4 * C_;

  float at[4], ap[4], ag[4];
  #pragma unroll
  for (int i = 0; i < 4; ++i) {
    at[i] = bt[dg * 4 + i]; ap[i] = bp[dg * 4 + i]; ag[i] = bg[dg * 4 + i];
  }

  #pragma unroll
  for (int c0 = 0; c0 < C_; c0 += 4) {
    float xv[4];
    #pragma unroll
    for (int j = 0; j < 4; ++j) xv[j] = xb[(size_t)(c0 + j) * N_];
    #pragma unroll
    for (int i = 0; i < 4; ++i) {
      const float4 wt4 = *(const float4*)&WtR[i * C_ + c0];
      const float4 wp4 = *(const float4*)&WpR[i * C_ + c0];
      const float4 wg4 = *(const float4*)&WgR[i * C_ + c0];
      at[i] = fmaf(wt4.x, xv[0], at[i]); at[i] = fmaf(wt4.y, xv[1], at[i]);
      at[i] = fmaf(wt4.z, xv[2], at[i]); at[i] = fmaf(wt4.w, xv[3], at[i]);
      ap[i] = fmaf(wp4.x, xv[0], ap[i]); ap[i] = fmaf(wp4.y, xv[1], ap[i]);
      ap[i] = fmaf(wp4.z, xv[2], ap[i]); ap[i] = fmaf(wp4.w, xv[3], ap[i]);
      ag[i] = fmaf(wg4.x, xv[0], ag[i]); ag[i] = fmaf(wg4.y, xv[1], ag[i]);
      ag[i] = fmaf(wg4.z, xv[2], ag[i]); ag[i] = fmaf(wg4.w, xv[3], ag[i]);
    }
  }

  uint2 wt2, wp2;
  wt2.x = (uint32_t)f2bf(at[0] * LOG2E) | ((uint32_t)f2bf(at[1] * LOG2E) << 16);
  wt2.y = (uint32_t)f2bf(at[2] * LOG2E) | ((uint32_t)f2bf(at[3] * LOG2E) << 16);
  wp2.x = (uint32_t)f2bf(ap[0]) | ((uint32_t)f2bf(ap[1]) << 16);
  wp2.y = (uint32_t)f2bf(ap[2]) | ((uint32_t)f2bf(ap[3]) << 16);
  *(uint2*)(theta_t + ((size_t)(b * N_) + n) * CI + dg * 4) = wt2;
  *(uint2*)(phi_t   + ((size_t)(b * N_) + n) * CI + dg * 4) = wp2;
  #pragma unroll
  for (int i = 0; i < 4; ++i)
    gmat[((size_t)(b * CI) + dg * 4 + i) * N_ + n] = f2bf(ag[i]);
}

// -------- Kernel 2: flash attention (r15: lean softmax, single fence) ------
__global__ __launch_bounds__(512, 2) void attn_kernel(
    const ushort* __restrict__ theta_t,
    const ushort* __restrict__ phi_t,
    const ushort* __restrict__ gmat,
    const float* __restrict__ Ww, const float* __restrict__ bw,
    const float* __restrict__ x, float* __restrict__ out)
{
  __shared__ union {
    ushort pt[8][2][16 * 64];     // per-wave ping-pong P tiles (main loop)
    float  accS[4][32][64];       // merge acc slots (merge phase)
    float  yl[32 * 66];           // y tile (after final merge sync)
  } Sh;
  __shared__ float mlS[4][8][64]; // merge m/l slots
  __shared__ float WwL[C_ * CI];

  const int tid = threadIdx.x;
  const int lane = tid & 63;
  const int mh = tid >> 6;        // wave = m-eighth 0..7
  const int bid = blockIdx.x;
  const int b = bid & 7;          // batch -> XCD slot (K/V L2-resident)
  const int n0 = (bid >> 3) * 64;
  const int g4 = lane >> 4;
  const int c16 = lane & 15;
  const int sw = (c16 & 7) << 4;

  #pragma unroll
  for (int i = 0; i < 4; ++i) WwL[tid + i * 512] = Ww[tid + i * 512];

  bf16x8 qfrag[4];
  #pragma unroll
  for (int s = 0; s < 4; ++s)
    qfrag[s] = *(const bf16x8*)(theta_t +
        ((size_t)(b * N_ + n0 + s * 16 + c16)) * CI + g4 * 8);

  f32x4 acc[4][2];
  f32x4 cinit[4];                 // = splat(-m_run[s]); lives in regs
  #pragma unroll
  for (int s = 0; s < 4; ++s) {
    acc[s][0] = (f32x4){0.f, 0.f, 0.f, 0.f};
    acc[s][1] = (f32x4){0.f, 0.f, 0.f, 0.f};
    cinit[s]  = (f32x4){0.f, 0.f, 0.f, 0.f};
  }
  float l_lane[4] = {0.f, 0.f, 0.f, 0.f};

  const int mq0 = mh * 512;
  const ushort* kbase = phi_t + ((size_t)(b * N_ + mq0 + c16)) * CI + g4 * 8;
  const ushort* vb0 = gmat + ((size_t)(b * CI + c16)) * N_ + mq0 + g4 * 8;
  const ushort* vb1 = vb0 + (size_t)16 * N_;

  char* pw[2][4]; const char* prd[2][2];
  #pragma unroll
  for (int pb = 0; pb < 2; ++pb) {
    #pragma unroll
    for (int mt = 0; mt < 4; ++mt)
      pw[pb][mt] = (char*)Sh.pt[mh][pb] + ((c16 * 128 + mt * 32 + g4 * 8) ^ sw);
    #pragma unroll
    for (int ks = 0; ks < 2; ++ks)
      prd[pb][ks] = (const char*)Sh.pt[mh][pb] +
                    ((c16 * 128 + ks * 64 + g4 * 16) ^ sw);
  }

  bf16x8 kf[4], kfn[4], vf0[2], vf1[2];
  #pragma unroll
  for (int mt = 0; mt < 4; ++mt)
    kfn[mt] = *(const bf16x8*)(kbase + (size_t)(mt * 16) * CI);

  const int NT = 8;               // 512 rows / 64 per tile
  for (int t = 0; t < NT; ++t) {
    #pragma unroll
    for (int mt = 0; mt < 4; ++mt) kf[mt] = kfn[mt];
    const int tn = (t + 1 < NT) ? t + 1 : t;
    #pragma unroll
    for (int mt = 0; mt < 4; ++mt)
      kfn[mt] = *(const bf16x8*)(kbase + (size_t)(tn * 64 + mt * 16) * CI);
    #pragma unroll
    for (int ks = 0; ks < 2; ++ks) {
      vf0[ks] = *(const bf16x8*)(vb0 + t * 64 + ks * 32);
      vf1[ks] = *(const bf16x8*)(vb1 + t * 64 + ks * 32);
    }

    #pragma unroll
    for (int s = 0; s < 4; ++s) {
      const int pb = s & 1;
      f32x4 f[4];
      #pragma unroll
      for (int mt = 0; mt < 4; ++mt)
        f[mt] = __builtin_amdgcn_mfma_f32_16x16x32_bf16(
            kf[mt], qfrag[s], cinit[s], 0, 0, 0);   // f = K.Q - m (free sub)

      float pv[4][4];
      #pragma unroll
      for (int mt = 0; mt < 4; ++mt) {
        #pragma unroll
        for (int rr = 0; rr < 4; ++rr)
          pv[mt][rr] = __builtin_amdgcn_exp2f(f[mt][rr]);
        l_lane[s] += (pv[mt][0] + pv[mt][1]) + (pv[mt][2] + pv[mt][3]);
      }
      #pragma unroll
      for (int mt = 0; mt < 4; ++mt) {
        uint2 wv;
        wv.x = cvt_pk_bf16(pv[mt][0], pv[mt][1]);
        wv.y = cvt_pk_bf16(pv[mt][2], pv[mt][3]);
        *(uint2*)pw[pb][mt] = wv;
      }
      // write->drain->read pinned by volatile asm + memory clobber
      asm volatile("s_waitcnt lgkmcnt(0)" ::: "memory");

      #pragma unroll
      for (int ks = 0; ks < 2; ++ks) {
        const bf16x8 pfrag = *(const bf16x8*)prd[pb][ks];
        acc[s][0] = __builtin_amdgcn_mfma_f32_16x16x32_bf16(
            vf0[ks], pfrag, acc[s][0], 0, 0, 0);
        acc[s][1] = __builtin_amdgcn_mfma_f32_16x16x32_bf16(
            vf1[ks], pfrag, acc[s][1], 0, 0, 0);
      }

      // l-threshold rescale: rare, exact power of 2; keeps l,p,acc in range.
      if (__any(l_lane[s] > 0x1p40f)) {
        const float sc = 0x1p-64f;
        acc[s][0] *= sc; acc[s][1] *= sc; l_lane[s] *= sc;
        #pragma unroll
        for (int rr = 0; rr < 4; ++rr) cinit[s][rr] -= 64.f;
      }
    }
  }

  // total l per q-column: sum the 4 g4 partials
  float m_run[4];
  #pragma unroll
  for (int s = 0; s < 4; ++s) {
    l_lane[s] += __shfl_xor(l_lane[s], 16);
    l_lane[s] += __shfl_xor(l_lane[s], 32);
    m_run[s] = -cinit[s][0];
  }

  // ---- split-m merge: max-aware flash combine, 3-round tree ----
  #pragma unroll
  for (int r = 4; r >= 1; r >>= 1) {
    __syncthreads();
    if (mh >= r && mh < 2 * r) {
      float* ad = &Sh.accS[mh - r][0][0] + lane;
      float* md = &mlS[mh - r][0][0] + lane;
      #pragma unroll
      for (int s = 0; s < 4; ++s) {
        #pragma unroll
        for (int rr = 0; rr < 4; ++rr) {
          ad[(s * 8 + rr) * 64]     = acc[s][0][rr];
          ad[(s * 8 + 4 + rr) * 64] = acc[s][1][rr];
        }
        md[s * 64]       = m_run[s];
        md[(4 + s) * 64] = l_lane[s];
      }
    }
    __syncthreads();
    if (mh < r) {
      const float* as_ = &Sh.accS[mh][0][0] + lane;
      const float* ms_ = &mlS[mh][0][0] + lane;
      #pragma unroll
      for (int s = 0; s < 4; ++s) {
        const float mb = ms_[s * 64];
        const float lb = ms_[(4 + s) * 64];
        const float mM = fmaxf(m_run[s], mb);
        const float ea = __builtin_amdgcn_exp2f(m_run[s] - mM);
        const float eb = __builtin_amdgcn_exp2f(mb - mM);
        #pragma unroll
        for (int rr = 0; rr < 4; ++rr) {
          acc[s][0][rr] = acc[s][0][rr] * ea + as_[(s * 8 + rr) * 64] * eb;
          acc[s][1][rr] = acc[s][1][rr] * ea + as_[(s * 8 + 4 + rr) * 64] * eb;
        }
        l_lane[s] = l_lane[s] * ea + lb * eb;
        m_run[s] = mM;
      }
    }
  }
  __syncthreads();                // all merge reads done; Sh reusable as Yl

  float* const Yl = Sh.yl;        // aliases dead pt/accS (barrier-ordered)
  if (mh == 0) {
    #pragma unroll
    for (int s = 0; s < 4; ++s) {
      const float inv = 1.0f / l_lane[s];
      const int q = s * 16 + c16;
      #pragma unroll
      for (int rr = 0; rr < 4; ++rr) {
        Yl[(g4 * 4 + rr) * 66 + q]      = acc[s][0][rr] * inv;
        Yl[(16 + g4 * 4 + rr) * 66 + q] = acc[s][1][rr] * inv;
      }
    }
  }
  __syncthreads();

  // ---- fused out-projection + residual: out = Ww @ y + bw + x ----
  const int nl = tid & 63;
  const int cg = tid >> 6;
  float oacc[8];
  #pragma unroll
  for (int i = 0; i < 8; ++i) oacc[i] = bw[cg * 8 + i];
  #pragma unroll
  for (int d = 0; d < CI; ++d) {
    const float yv = Yl[d * 66 + nl];
    #pragma unroll
    for (int i = 0; i < 8; ++i)
      oacc[i] = fmaf(WwL[(cg * 8 + i) * CI + d], yv, oacc[i]);
  }
  #pragma unroll
  for (int i = 0; i < 8; ++i) {
    const size_t idx = ((size_t)(b * C_ + cg * 8 + i)) * N_ + n0 + nl;
    out[idx] = oacc[i] + x[idx];
  }
}

extern "C" void kernel_launch(void* const* d_in, const int* in_sizes, int n_in,
                              void* d_out, int out_size, void* d_ws, size_t ws_size,
                              hipStream_t stream) {
  const float* x  = (const float*)d_in[0];
  const float* Wg = (const float*)d_in[1];
  const float* bg = (const float*)d_in[2];
  const float* Wt = (const float*)d_in[3];
  const float* bt = (const float*)d_in[4];
  const float* Wp = (const float*)d_in[5];
  const float* bp = (const float*)d_in[6];
  const float* Ww = (const float*)d_in[7];
  const float* bw = (const float*)d_in[8];
  float* out = (float*)d_out;

  char* ws = (char*)d_ws;
  ushort* theta_t = (ushort*)(ws);
  ushort* phi_t   = (ushort*)(ws + (size_t)2 * 1024 * 1024);
  ushort* gmat    = (ushort*)(ws + (size_t)4 * 1024 * 1024);

  proj_kernel<<<dim3(N_ / 64, B_), 512, 0, stream>>>(
      x, Wg, bg, Wt, bt, Wp, bp, theta_t, phi_t, gmat);
  attn_kernel<<<dim3((N_ / 64) * B_), 512, 0, stream>>>(
      theta_t, phi_t, gmat, Ww, bw, x, out);
}